// Round 1
// baseline (252.206 us; speedup 1.0000x reference)
//
#include <hip/hip_runtime.h>
#include <cstdint>

// Problem constants
#define BB 4
#define TT 2048      // TQ == TK
#define DD 512
#define HH 8
#define DH 64

using bf16x8 = __attribute__((ext_vector_type(8))) __bf16;
using f32x4  = __attribute__((ext_vector_type(4))) float;
using us8    = __attribute__((ext_vector_type(8))) unsigned short;
using us4    = __attribute__((ext_vector_type(4))) unsigned short;

typedef const __attribute__((address_space(1))) unsigned int* as1cp;
typedef __attribute__((address_space(3))) unsigned int* as3p;

__device__ __forceinline__ void gload16(const void* g, void* l) {
  __builtin_amdgcn_global_load_lds((as1cp)(uintptr_t)g,
                                   (as3p)(unsigned int)(uintptr_t)l, 16, 0, 0);
}

__device__ __forceinline__ unsigned short f2bf(float x) {
  unsigned int u = __float_as_uint(x);
  u += 0x7fffu + ((u >> 16) & 1u);
  return (unsigned short)(u >> 16);
}
__device__ __forceinline__ float bf2f(unsigned short u) {
  return __uint_as_float(((unsigned int)u) << 16);
}
__device__ __forceinline__ f32x4 MFMA(bf16x8 a, bf16x8 b, f32x4 c) {
  return __builtin_amdgcn_mfma_f32_16x16x32_bf16(a, b, c, 0, 0, 0);
}

// ---------------- 1. convert inputs to bf16 ----------------
__global__ __launch_bounds__(256) void cvt_inputs(const float4* __restrict__ q,
                                                  const float4* __restrict__ k,
                                                  us4* __restrict__ qb,
                                                  us4* __restrict__ kb) {
  size_t i = (size_t)blockIdx.x * 256 + threadIdx.x;   // one float4 each
  float4 a = q[i];
  us4 o; o[0] = f2bf(a.x); o[1] = f2bf(a.y); o[2] = f2bf(a.z); o[3] = f2bf(a.w);
  qb[i] = o;
  float4 b = k[i];
  us4 p; p[0] = f2bf(b.x); p[1] = f2bf(b.y); p[2] = f2bf(b.z); p[3] = f2bf(b.w);
  kb[i] = p;
}

// ---------------- 2. weight transpose + convert: Wt[z][n][k] = bf16(W[z][k][n]) ----------------
__global__ __launch_bounds__(256) void cvt_w(const float* __restrict__ Wq,
                                             const float* __restrict__ Wk,
                                             const float* __restrict__ Wv,
                                             unsigned short* __restrict__ Wt) {
  __shared__ float tile[32][33];
  int z = blockIdx.z;
  const float* W = (z == 0) ? Wq : (z == 1) ? Wk : Wv;
  int k0 = blockIdx.x * 32, n0 = blockIdx.y * 32;
  int r = threadIdx.x >> 5, c = threadIdx.x & 31;
#pragma unroll
  for (int p = 0; p < 4; ++p)
    tile[r + p * 8][c] = W[(size_t)(k0 + r + p * 8) * DD + n0 + c];
  __syncthreads();
  unsigned short* o = Wt + (size_t)z * DD * DD;
#pragma unroll
  for (int p = 0; p < 4; ++p)
    o[(size_t)(n0 + r + p * 8) * DD + k0 + c] = f2bf(tile[c][r + p * 8]);
}

// ---------------- 3. projection GEMM: out = relu(A @ W + b), bf16 out ----------------
// A: [8192, 512] bf16 ; Wt: [512(n), 512(k)] bf16 ; 128x128 tile, BK=32, 4 waves
__global__ __launch_bounds__(256) void gemm_proj(const unsigned short* __restrict__ qb,
                                                 const unsigned short* __restrict__ kb,
                                                 const unsigned short* __restrict__ Wt,
                                                 const float* __restrict__ bq,
                                                 const float* __restrict__ bk,
                                                 const float* __restrict__ bv,
                                                 unsigned short* __restrict__ Qp,
                                                 unsigned short* __restrict__ Kp,
                                                 unsigned short* __restrict__ Vp) {
  int z = blockIdx.z;
  const unsigned short* A  = (z == 0) ? qb : kb;
  const unsigned short* Bt = Wt + (size_t)z * DD * DD;
  const float* bias = (z == 0) ? bq : (z == 1) ? bk : bv;
  unsigned short* out = (z == 0) ? Qp : (z == 1) ? Kp : Vp;

  __shared__ __align__(16) unsigned short As[128 * 32];
  __shared__ __align__(16) unsigned short Bs[128 * 32];

  int mb = blockIdx.x * 128, nb = blockIdx.y * 128;
  int w = threadIdx.x >> 6, lane = threadIdx.x & 63;
  int l15 = lane & 15, lg = lane >> 4;
  int wr = (w >> 1) * 64, wc = (w & 1) * 64;

  f32x4 acc[4][4] = {};

  for (int kt = 0; kt < DD / 32; ++kt) {
    int kk = kt * 32;
    int t = threadIdx.x;
#pragma unroll
    for (int it = 0; it < 2; ++it) {
      int c = t + it * 256;              // chunk: 16B, r=c>>2 row, (c&3)*8 col
      gload16(A  + (size_t)(mb + (c >> 2)) * DD + kk + (c & 3) * 8, As + c * 8);
      gload16(Bt + (size_t)(nb + (c >> 2)) * DD + kk + (c & 3) * 8, Bs + c * 8);
    }
    __syncthreads();
    bf16x8 af[4], bf[4];
#pragma unroll
    for (int m = 0; m < 4; ++m)
      af[m] = *(const bf16x8*)&As[(wr + m * 16 + l15) * 32 + lg * 8];
#pragma unroll
    for (int n = 0; n < 4; ++n)
      bf[n] = *(const bf16x8*)&Bs[(wc + n * 16 + l15) * 32 + lg * 8];
#pragma unroll
    for (int m = 0; m < 4; ++m)
#pragma unroll
      for (int n = 0; n < 4; ++n)
        acc[m][n] = MFMA(af[m], bf[n], acc[m][n]);
    __syncthreads();
  }

#pragma unroll
  for (int m = 0; m < 4; ++m)
#pragma unroll
    for (int n = 0; n < 4; ++n)
#pragma unroll
      for (int i = 0; i < 4; ++i) {
        int row = mb + wr + m * 16 + lg * 4 + i;
        int col = nb + wc + n * 16 + l15;
        float v = acc[m][n][i] + bias[col];
        v = fmaxf(v, 0.f);
        out[(size_t)row * DD + col] = f2bf(v);
      }
}

// ---------------- 4. V transpose: Vp[B*TK, D] -> Vt[B, D, TK] ----------------
__global__ __launch_bounds__(256) void transpose_v(const unsigned short* __restrict__ Vp,
                                                   unsigned short* __restrict__ Vt) {
  __shared__ unsigned short tile[64][72];
  int b = blockIdx.z, k0 = blockIdx.x * 64, d0 = blockIdx.y * 64;
  int t = threadIdx.x;
  int r = t >> 3, c8 = (t & 7) * 8;
#pragma unroll
  for (int p = 0; p < 2; ++p) {
    int row = r + p * 32;
    us8 v = *(const us8*)&Vp[(size_t)(b * TT + k0 + row) * DD + d0 + c8];
#pragma unroll
    for (int j = 0; j < 8; ++j) tile[row][c8 + j] = v[j];
  }
  __syncthreads();
#pragma unroll
  for (int p = 0; p < 2; ++p) {
    int dr = r + p * 32;
    us8 o;
#pragma unroll
    for (int j = 0; j < 8; ++j) o[j] = tile[c8 + j][dr];
    *(us8*)&Vt[((size_t)b * DD + d0 + dr) * TT + k0 + c8] = o;
  }
}

// ---------------- 5. masks: qmask/kmask[b][h][t] = (sum over head chunk > 0) ----------------
__global__ __launch_bounds__(256) void mask_kernel(const unsigned short* __restrict__ Qp,
                                                   const unsigned short* __restrict__ Kp,
                                                   float* __restrict__ qmask,
                                                   float* __restrict__ kmask) {
  int idx = blockIdx.x * 256 + threadIdx.x;   // 2 * 65536 total
  const unsigned short* src;
  float* dst;
  int r;
  if (idx < 65536) { src = Qp; dst = qmask; r = idx; }
  else             { src = Kp; dst = kmask; r = idx - 65536; }
  int row = r >> 3, h = r & 7;
  const unsigned short* p = src + (size_t)row * DD + h * DH;
  float s = 0.f;
#pragma unroll
  for (int j = 0; j < 64; j += 8) {
    us8 v = *(const us8*)(p + j);
#pragma unroll
    for (int e = 0; e < 8; ++e) s += bf2f(v[e]);
  }
  int b = row >> 11, tpos = row & (TT - 1);
  dst[((size_t)b * HH + h) * TT + tpos] = (s > 0.f) ? 1.f : 0.f;
}

// ---------------- 6. flash attention ----------------
// grid (TQ/64, H, B), 256 threads (4 waves, 16 q-rows each), KV tile = 64
__global__ __launch_bounds__(256) void attn_kernel(const unsigned short* __restrict__ Qp,
                                                   const unsigned short* __restrict__ Kp,
                                                   const unsigned short* __restrict__ Vt,
                                                   const float* __restrict__ kmask,
                                                   const float* __restrict__ qmask,
                                                   float* __restrict__ O) {
  __shared__ __align__(16) unsigned short Ks[64 * 64];
  __shared__ __align__(16) unsigned short Vs[64 * 64];
  __shared__ __align__(16) unsigned short Ps[4][16 * 64];

  const int qt = blockIdx.x, h = blockIdx.y, b = blockIdx.z;
  const int w = threadIdx.x >> 6, lane = threadIdx.x & 63;
  const int l15 = lane & 15, lg = lane >> 4;

  const unsigned short* qptr =
      Qp + ((size_t)(b * TT + qt * 64 + w * 16 + l15)) * DD + h * DH;
  bf16x8 qf0 = *(const bf16x8*)(qptr + lg * 8);
  bf16x8 qf1 = *(const bf16x8*)(qptr + 32 + lg * 8);

  float m_i[4], l_i[4];
  f32x4 oa[4] = {};
#pragma unroll
  for (int i = 0; i < 4; ++i) { m_i[i] = -INFINITY; l_i[i] = 0.f; }

  const unsigned short* kg = Kp + ((size_t)b * TT) * DD + h * DH;
  const unsigned short* vg = Vt + ((size_t)b * DD + h * DH) * TT;
  const float* km = kmask + ((size_t)(b * HH + h)) * TT;
  unsigned short* pw = &Ps[w][0];

  for (int kt = 0; kt < TT / 64; ++kt) {
    {  // stage K and V^T tiles (64x64 bf16 each), XOR-swizzled source, linear LDS dest
      int t = threadIdx.x;
#pragma unroll
      for (int it = 0; it < 2; ++it) {
        int c = t + it * 256;
        int r = c >> 3, j = c & 7;
        int js = j ^ (r & 7);
        gload16(kg + (size_t)(kt * 64 + r) * DD + js * 8, Ks + c * 8);
        gload16(vg + (size_t)r * TT + kt * 64 + js * 8, Vs + c * 8);
      }
    }
    __syncthreads();

    // S = Q K^T  (per wave: 16 q-rows x 64 k-cols)
    f32x4 s[4] = {};
#pragma unroll
    for (int ch = 0; ch < 2; ++ch) {
      bf16x8 qf = ch ? qf1 : qf0;
#pragma unroll
      for (int f = 0; f < 4; ++f) {
        int krow = f * 16 + l15;
        int j = ch * 4 + lg;
        bf16x8 kf = *(const bf16x8*)&Ks[krow * 64 + ((j ^ (krow & 7)) << 3)];
        s[f] = MFMA(qf, kf, s[f]);
      }
    }

    // mask + scale
#pragma unroll
    for (int f = 0; f < 4; ++f) {
      float mk = km[kt * 64 + f * 16 + l15];
#pragma unroll
      for (int i = 0; i < 4; ++i)
        s[f][i] = (mk > 0.f) ? s[f][i] * 0.125f : -1e9f;
    }

    // online softmax: row r = lg*4+i lives on the 16 lanes sharing lg
    float rmax[4];
#pragma unroll
    for (int i = 0; i < 4; ++i)
      rmax[i] = fmaxf(fmaxf(s[0][i], s[1][i]), fmaxf(s[2][i], s[3][i]));
#pragma unroll
    for (int xm = 1; xm < 16; xm <<= 1)
#pragma unroll
      for (int i = 0; i < 4; ++i)
        rmax[i] = fmaxf(rmax[i], __shfl_xor(rmax[i], xm));

    float alpha[4], rsum[4];
#pragma unroll
    for (int i = 0; i < 4; ++i) {
      float mn = fmaxf(m_i[i], rmax[i]);
      alpha[i] = __expf(m_i[i] - mn);
      m_i[i] = mn;
      rsum[i] = 0.f;
    }
#pragma unroll
    for (int f = 0; f < 4; ++f)
#pragma unroll
      for (int i = 0; i < 4; ++i) {
        float p = __expf(s[f][i] - m_i[i]);
        s[f][i] = p;
        rsum[i] += p;
      }
#pragma unroll
    for (int xm = 1; xm < 16; xm <<= 1)
#pragma unroll
      for (int i = 0; i < 4; ++i)
        rsum[i] += __shfl_xor(rsum[i], xm);
#pragma unroll
    for (int i = 0; i < 4; ++i)
      l_i[i] = l_i[i] * alpha[i] + rsum[i];
#pragma unroll
    for (int f = 0; f < 4; ++f)
#pragma unroll
      for (int i = 0; i < 4; ++i)
        oa[f][i] *= alpha[i];

    // P -> per-wave LDS (bf16, same XOR swizzle on 16B chunks)
#pragma unroll
    for (int f = 0; f < 4; ++f) {
      int o_us = f * 16 + l15;
#pragma unroll
      for (int i = 0; i < 4; ++i) {
        int row = lg * 4 + i;
        int sw = (((o_us >> 3) ^ (row & 7)) << 3) | (o_us & 7);
        pw[row * 64 + sw] = f2bf(s[f][i]);
      }
    }

    // O += P @ V  (Vt rows are output dims, contiguous along k)
#pragma unroll
    for (int ch = 0; ch < 2; ++ch) {
      int j = ch * 4 + lg;
      bf16x8 pa = *(const bf16x8*)&pw[l15 * 64 + ((j ^ (l15 & 7)) << 3)];
#pragma unroll
      for (int f = 0; f < 4; ++f) {
        int vrow = f * 16 + l15;
        bf16x8 vf = *(const bf16x8*)&Vs[vrow * 64 + ((j ^ (vrow & 7)) << 3)];
        oa[f] = MFMA(pa, vf, oa[f]);
      }
    }
    __syncthreads();
  }

  // epilogue: divide by l, apply query mask, write f32 O[b, q, h*64+col]
  const float* qm = qmask + ((size_t)(b * HH + h)) * TT + qt * 64 + w * 16;
  float* ob = O + ((size_t)(b * TT + qt * 64 + w * 16)) * DD + h * DH;
#pragma unroll
  for (int i = 0; i < 4; ++i) {
    int row = lg * 4 + i;
    float sc = qm[row] / l_i[i];
#pragma unroll
    for (int f = 0; f < 4; ++f)
      ob[(size_t)row * DD + f * 16 + l15] = oa[f][i] * sc;
  }
}

// ---------------- 7. residual + LayerNorm ----------------
__global__ __launch_bounds__(256) void ln_kernel(const float* __restrict__ O,
                                                 const float* __restrict__ qin,
                                                 const float* __restrict__ gamma,
                                                 const float* __restrict__ beta,
                                                 float* __restrict__ out) {
  int row = blockIdx.x * 4 + (threadIdx.x >> 6);
  int lane = threadIdx.x & 63;
  size_t base = (size_t)row * DD + lane * 8;
  const float4* o4 = (const float4*)(O + base);
  const float4* q4 = (const float4*)(qin + base);
  float4 a = o4[0], b2 = o4[1], c = q4[0], d2 = q4[1];
  float v[8];
  v[0] = a.x + c.x; v[1] = a.y + c.y; v[2] = a.z + c.z; v[3] = a.w + c.w;
  v[4] = b2.x + d2.x; v[5] = b2.y + d2.y; v[6] = b2.z + d2.z; v[7] = b2.w + d2.w;
  float s = 0.f, s2 = 0.f;
#pragma unroll
  for (int j = 0; j < 8; ++j) { s += v[j]; s2 += v[j] * v[j]; }
#pragma unroll
  for (int xm = 1; xm < 64; xm <<= 1) {
    s += __shfl_xor(s, xm);
    s2 += __shfl_xor(s2, xm);
  }
  float mu = s * (1.0f / DD);
  float var = s2 * (1.0f / DD) - mu * mu;
  float rs = rsqrtf(var + 1e-3f);
  const float* g = gamma + lane * 8;
  const float* bb = beta + lane * 8;
  float* ob = out + base;
#pragma unroll
  for (int j = 0; j < 8; ++j) ob[j] = (v[j] - mu) * rs * g[j] + bb[j];
}

// ---------------- launch ----------------
extern "C" void kernel_launch(void* const* d_in, const int* in_sizes, int n_in,
                              void* d_out, int out_size, void* d_ws, size_t ws_size,
                              hipStream_t stream) {
  (void)in_sizes; (void)n_in; (void)out_size; (void)ws_size;
  const float* queries = (const float*)d_in[0];
  const float* keys_in = (const float*)d_in[1];
  const float* Wq = (const float*)d_in[2];
  const float* bq = (const float*)d_in[3];
  const float* Wk = (const float*)d_in[4];
  const float* bk = (const float*)d_in[5];
  const float* Wv = (const float*)d_in[6];
  const float* bv = (const float*)d_in[7];
  const float* gamma = (const float*)d_in[8];
  const float* beta  = (const float*)d_in[9];
  float* out = (float*)d_out;

  char* ws = (char*)d_ws;
  // layout (MB): [0,8) qb | [8,16) kb    -- later aliased by O f32 [0,16)
  unsigned short* qb = (unsigned short*)(ws);
  unsigned short* kb = (unsigned short*)(ws + (8ull << 20));
  float*          O  = (float*)(ws);
  unsigned short* Qp = (unsigned short*)(ws + (16ull << 20));
  unsigned short* Kp = (unsigned short*)(ws + (24ull << 20));
  unsigned short* Vp = (unsigned short*)(ws + (32ull << 20));
  unsigned short* Vt = (unsigned short*)(ws + (40ull << 20));
  unsigned short* Wt = (unsigned short*)(ws + (48ull << 20));
  float* kmaskp = (float*)(ws + (50ull << 20));
  float* qmaskp = (float*)(ws + (50ull << 20) + (256ull << 10));

  cvt_inputs<<<4096, 256, 0, stream>>>((const float4*)queries, (const float4*)keys_in,
                                       (us4*)qb, (us4*)kb);
  cvt_w<<<dim3(16, 16, 3), 256, 0, stream>>>(Wq, Wk, Wv, Wt);
  gemm_proj<<<dim3(64, 4, 3), 256, 0, stream>>>(qb, kb, Wt, bq, bk, bv, Qp, Kp, Vp);
  transpose_v<<<dim3(32, 8, 4), 256, 0, stream>>>(Vp, Vt);
  mask_kernel<<<512, 256, 0, stream>>>(Qp, Kp, qmaskp, kmaskp);
  attn_kernel<<<dim3(32, 8, 4), 256, 0, stream>>>(Qp, Kp, Vt, kmaskp, qmaskp, O);
  ln_kernel<<<2048, 256, 0, stream>>>(O, queries, gamma, beta, out);
}